// Round 1
// baseline (109.974 us; speedup 1.0000x reference)
//
#include <hip/hip_runtime.h>
#include <math.h>

// One block (256 threads) per video row. T = 4096 = 256 chunks x 16 (CH == DELTA).
// Thread j owns chunk j: loads it as float4s, keeps z[16] in registers, computes
// chunk maxima in registers, stores masked p1 to LDS (p2 = 1-p1 recomputed on read).
// Prefix/suffix cummax over 256 chunk maxima via wave shuffles + 4-wave combine.
// Final reduction is fused: last-arriving block (atomic ticket in ws, re-zeroed
// each iteration by a 4-byte memset node) reduces all partials in EXACTLY the
// same summation order as the old lftc_reduce kernel -> bit-identical output.

#define T_LEN 4096
#define NCH   256
#define CH    16
#define PADS  17       // padded chunk stride: bank (17j+i)%32 -> 2-way max (free)
#define NEGV  (-1e30f)
#define NEGH  (-5e29f)
#define CTR_F 4096     // float index of the completion counter in ws (byte 16384)

__device__ __forceinline__ float frcp(float x) { return __builtin_amdgcn_rcpf(x); }

__device__ __forceinline__ void amax_comb(float& v, int& i, float ov, int oi) {
  // argmax, first-occurrence (smallest index) tie-break — matches jnp.argmax
  if (ov > v || (ov == v && oi < i)) { v = ov; i = oi; }
}

__global__ __launch_bounds__(256, 4) void lftc_main(
    const float* __restrict__ s1s2,  // [B, T, 2]
    const float* __restrict__ act,   // [B, T]
    const int*   __restrict__ lens,  // [B]
    const float* __restrict__ vls,   // [B]
    float* __restrict__ ws,          // [B, 2] partials + counter at CTR_F
    float* __restrict__ out,         // [2]
    int B)
{
  __shared__ float P1s[NCH * PADS];          // masked p1 (p2 = 1-p1 where valid)
  __shared__ float cm1[NCH];                 // inclusive prefix-max of chunk p1-maxima
  __shared__ float cm2[NCH];                 // inclusive suffix-max of chunk p2-maxima
  __shared__ float wag1[4], wag2[4];
  __shared__ float redv[4];  __shared__ int redi[4];
  __shared__ float redv2[4]; __shared__ int redi2[4];
  __shared__ float redv3[4]; __shared__ int redi3[4];
  __shared__ float fa0[4], fa1[4];
  __shared__ int   s_last;

  const int b    = blockIdx.x;
  const int tid  = threadIdx.x;
  const int lane = tid & 63;
  const int wv   = tid >> 6;
  const int len  = lens[b];
  const float w  = vls[b];

  const float* __restrict__ srow = s1s2 + (size_t)b * T_LEN * 2;
  const float* __restrict__ zrow = act  + (size_t)b * T_LEN;

  const int j    = tid;
  const int base = j * CH;

  // ---------- phase 1: batch-load chunk, softmax via single exp, chunk maxima ----------
  float4 sv[8];
  {
    const float4* sp4 = reinterpret_cast<const float4*>(srow + 2 * base);
#pragma unroll
    for (int k = 0; k < 8; k++) sv[k] = sp4[k];
  }
  float4 zv[4];
  {
    const float4* zp4 = reinterpret_cast<const float4*>(zrow + base);
#pragma unroll
    for (int k = 0; k < 4; k++) zv[k] = zp4[k];
  }
  const float* sf = reinterpret_cast<const float*>(sv);
  float z[16];
  {
    const float* zf = reinterpret_cast<const float*>(zv);
#pragma unroll
    for (int i = 0; i < 16; i++) z[i] = zf[i];
  }

  float m1 = NEGV, m2 = NEGV, sp_part = 0.f;
#pragma unroll
  for (int i = 0; i < CH; i++) {
    float lx = sf[2 * i], ly = sf[2 * i + 1];
    float p  = frcp(1.f + __expf(ly - lx));       // p1 = softmax[...,0]
    bool  v  = (base + i) < len;
    float p1m = v ? p : NEGV;
    float p2m = v ? 1.f - p : NEGV;
    P1s[j * PADS + i] = p1m;
    m1 = fmaxf(m1, p1m);
    m2 = fmaxf(m2, p2m);
    float zi = z[i];
    if (v) sp_part += fmaxf(zi, 0.f) + __logf(1.f + __expf(-fabsf(zi)));  // softplus(z)
  }

  // ---------- phase 2: prefix-max scan (m1) + suffix-max scan (m2) over 256 chunks ----------
  {
    float pm = m1;
#pragma unroll
    for (int off = 1; off < 64; off <<= 1) {
      float o = __shfl_up(pm, off);
      if (lane >= off) pm = fmaxf(pm, o);
    }
    float sm = m2;
#pragma unroll
    for (int off = 1; off < 64; off <<= 1) {
      float o = __shfl_down(sm, off);
      if (lane + off < 64) sm = fmaxf(sm, o);
    }
    if (lane == 63) wag1[wv] = pm;   // wave total (prefix side)
    if (lane == 0)  wag2[wv] = sm;   // wave total (suffix side)
    __syncthreads();
    float addp = NEGV, adds = NEGV;
#pragma unroll
    for (int q = 0; q < 4; q++) {
      if (q < wv) addp = fmaxf(addp, wag1[q]);
      if (q > wv) adds = fmaxf(adds, wag2[q]);
    }
    cm1[tid] = fmaxf(pm, addp);
    cm2[tid] = fmaxf(sm, adds);
    __syncthreads();   // also publishes P1s
  }

  // ---------- phase 3: score[t] = pre[t-16] * sigmoid(z[t]) * suf[t+16]; argmax -> ac ----------
  float best = NEGV;
  int   bidx = base;    // all-masked rows reduce to index 0 (matches jnp.argmax)
  {
    float rs[CH];       // suf_s for this chunk (reverse scan over neighbor chunk j+1)
    if (j <= NCH - 2) {
      float run = (j + 2 <= NCH - 1) ? cm2[j + 2] : NEGV;
      const int b2 = (j + 1) * PADS;
#pragma unroll
      for (int i = CH - 1; i >= 0; --i) {
        float p1n = P1s[b2 + i];
        float p2n = (p1n > NEGH) ? 1.f - p1n : NEGV;
        run = fmaxf(run, p2n);
        rs[i] = run;
      }
    }
    float prerun = (j >= 2) ? cm1[j - 2] : NEGV;
    const int b1 = (j - 1) * PADS;
#pragma unroll
    for (int i = 0; i < CH; i++) {
      float pre_s = NEGV;
      if (j >= 1) { prerun = fmaxf(prerun, P1s[b1 + i]); pre_s = prerun; }
      float suf_s = (j <= NCH - 2) ? rs[i] : NEGV;
      int t = base + i;
      if (pre_s > NEGH && suf_s > NEGH && t < len) {
        float pa = frcp(1.f + __expf(-z[i]));
        float sc = (pre_s * pa) * suf_s;
        if (sc > best) { best = sc; bidx = t; }   // strict > keeps first occurrence
      }
    }
  }
#pragma unroll
  for (int off = 32; off; off >>= 1) {
    float ov = __shfl_down(best, off);
    int   oi = __shfl_down(bidx, off);
    amax_comb(best, bidx, ov, oi);
  }
  if (lane == 0) { redv[wv] = best; redi[wv] = bidx; }
  __syncthreads();
  // every thread combines the 4 wave candidates redundantly (saves one barrier;
  // integer argmax -> identical result in all threads, bit-exact vs broadcast)
  int ac;
  {
    float v = redv[0]; int i = redi[0];
#pragma unroll
    for (int q = 1; q < 4; q++) amax_comb(v, i, redv[q], redi[q]);
    ac = i;
  }

  // ---------- phase 4: s1 = argmax p1m on [0, ac-16]; s2 = argmax p2m on [ac+16, T) ----------
  float v1 = NEGV; int i1 = 0;
  float v2 = NEGV; int i2 = 0;
  {
    const int e1   = ac - CH;
    const int s2lo = ac + CH;
#pragma unroll
    for (int k = 0; k < CH; k++) {
      int t = base + k;
      float p1v = P1s[j * PADS + k];
      if (t <= e1 && p1v > v1) { v1 = p1v; i1 = t; }
      float p2v = (p1v > NEGH) ? 1.f - p1v : NEGV;
      if (t >= s2lo && p2v > v2) { v2 = p2v; i2 = t; }
    }
#pragma unroll
    for (int off = 32; off; off >>= 1) {
      float ov1 = __shfl_down(v1, off); int oi1 = __shfl_down(i1, off);
      amax_comb(v1, i1, ov1, oi1);
      float ov2 = __shfl_down(v2, off); int oi2 = __shfl_down(i2, off);
      amax_comb(v2, i2, ov2, oi2);
    }
    if (lane == 0) { redv2[wv] = v1; redi2[wv] = i1; redv3[wv] = v2; redi3[wv] = i2; }
  }

  // ---------- phase 5: action window correction + block sum + partial output ----------
  if (tid < 9) {
    int t = ac - 4 + tid;
    if (t >= 0 && t < len) {
      float zc = zrow[t];
      float b0 = fmaxf(zc, 0.f) + __logf(1.f + __expf(-fabsf(zc)));  // softplus(z)
      sp_part += 10.f * (b0 - zc) - b0;   // 10*softplus(-z) replaces softplus(z)
    }
  }
  float s = sp_part;
#pragma unroll
  for (int off = 32; off; off >>= 1) s += __shfl_down(s, off);
  if (lane == 0) wag1[wv] = s;
  __syncthreads();
  if (tid == 0) {
    float tot = wag1[0] + wag1[1] + wag1[2] + wag1[3];

    float sv1 = redv2[0]; int s1i = redi2[0];
    float sv2 = redv3[0]; int s2i = redi3[0];
    for (int q = 1; q < 4; q++) {
      amax_comb(sv1, s1i, redv2[q], redi2[q]);
      amax_comb(sv2, s2i, redv3[q], redi3[q]);
    }
    // state CE: -log_softmax[s1,0] = softplus(l1-l0); -log_softmax[s2,1] = softplus(l0-l1)
    float a0 = srow[2 * (size_t)s1i],     a1 = srow[2 * (size_t)s1i + 1];
    float c0 = srow[2 * (size_t)s2i],     c1 = srow[2 * (size_t)s2i + 1];
    float d1 = a1 - a0;
    float loss1 = fmaxf(d1, 0.f) + __logf(1.f + __expf(-fabsf(d1)));
    float d2 = c0 - c1;
    float loss2 = fmaxf(d2, 0.f) + __logf(1.f + __expf(-fabsf(d2)));

    ws[2 * (size_t)b]     = w * (loss1 + loss2);
    ws[2 * (size_t)b + 1] = 0.2f * w * tot;

    // release our partials, then take a ticket; last block does the final reduce
    __threadfence();
    unsigned old = atomicAdd(reinterpret_cast<unsigned int*>(ws + CTR_F), 1u);
    s_last = (old == (unsigned)(B - 1)) ? 1 : 0;
  }
  __syncthreads();

  // ---------- fused final reduction (exact replica of old lftc_reduce order) ----------
  if (s_last) {
    float s0 = 0.f, s1 = 0.f;
    for (int i = tid; i < B; i += 256) {
      // agent-scope loads bypass L1 so other XCDs' released partials are seen
      s0 += __hip_atomic_load(ws + 2 * (size_t)i,     __ATOMIC_RELAXED, __HIP_MEMORY_SCOPE_AGENT);
      s1 += __hip_atomic_load(ws + 2 * (size_t)i + 1, __ATOMIC_RELAXED, __HIP_MEMORY_SCOPE_AGENT);
    }
#pragma unroll
    for (int off = 32; off; off >>= 1) {
      s0 += __shfl_down(s0, off);
      s1 += __shfl_down(s1, off);
    }
    if (lane == 0) { fa0[wv] = s0; fa1[wv] = s1; }
    __syncthreads();
    if (tid == 0) {
      out[0] = fa0[0] + fa0[1] + fa0[2] + fa0[3];
      out[1] = fa1[0] + fa1[1] + fa1[2] + fa1[3];
    }
  }
}

extern "C" void kernel_launch(void* const* d_in, const int* in_sizes, int n_in,
                              void* d_out, int out_size, void* d_ws, size_t ws_size,
                              hipStream_t stream) {
  const float* s1s2 = (const float*)d_in[0];
  const float* act  = (const float*)d_in[1];
  const int*   lens = (const int*)d_in[2];
  const float* vls  = (const float*)d_in[3];
  float* out = (float*)d_out;
  float* ws  = (float*)d_ws;

  const int B = in_sizes[2];   // lens has B elements; T fixed at 4096

  // re-arm the completion ticket (workspace is re-poisoned every iteration)
  hipMemsetAsync((char*)d_ws + CTR_F * sizeof(float), 0, sizeof(unsigned int), stream);
  lftc_main<<<B, 256, 0, stream>>>(s1s2, act, lens, vls, ws, out, B);
}

// Round 2
// 99.562 us; speedup vs baseline: 1.1046x; 1.1046x over previous
//
#include <hip/hip_runtime.h>
#include <math.h>

// One block (256 threads) per video row. T = 4096 = 256 chunks x 16 (CH == DELTA).
// Thread j owns chunk j: loads it as float4s, keeps z[16] in registers, computes
// chunk maxima in registers, stores masked p1 to LDS (p2 = 1-p1 recomputed on read).
// Prefix/suffix cummax over 256 chunk maxima via wave shuffles + 4-wave combine.
// Per-block partial losses go to d_ws; a second tiny kernel reduces to d_out.
//
// NOTE (R1 post-mortem): single-kernel fusion via threadfence+atomic ticket was
// tried and REGRESSED +11 us — per-block device-scope release on gfx950 costs an
// L2 writeback per block (XCD L2s non-coherent) + an extra graph node for the
// ticket re-arm. The separate reduce launch is the cheap device-wide barrier.

#define T_LEN 4096
#define NCH   256
#define CH    16
#define PADS  17       // padded chunk stride: bank (17j+i)%32 -> 2-way max (free)
#define NEGV  (-1e30f)
#define NEGH  (-5e29f)

__device__ __forceinline__ float frcp(float x) { return __builtin_amdgcn_rcpf(x); }

__device__ __forceinline__ void amax_comb(float& v, int& i, float ov, int oi) {
  // argmax, first-occurrence (smallest index) tie-break — matches jnp.argmax
  if (ov > v || (ov == v && oi < i)) { v = ov; i = oi; }
}

__global__ __launch_bounds__(256, 4) void lftc_main(
    const float* __restrict__ s1s2,  // [B, T, 2]
    const float* __restrict__ act,   // [B, T]
    const int*   __restrict__ lens,  // [B]
    const float* __restrict__ vls,   // [B]
    float* __restrict__ ws)          // [B, 2]: {state_partial, action_partial}
{
  __shared__ float P1s[NCH * PADS];          // masked p1 (p2 = 1-p1 where valid)
  __shared__ float cm1[NCH];                 // inclusive prefix-max of chunk p1-maxima
  __shared__ float cm2[NCH];                 // inclusive suffix-max of chunk p2-maxima
  __shared__ float wag1[4], wag2[4];
  __shared__ float redv[4];  __shared__ int redi[4];
  __shared__ float redv2[4]; __shared__ int redi2[4];
  __shared__ float redv3[4]; __shared__ int redi3[4];

  const int b    = blockIdx.x;
  const int tid  = threadIdx.x;
  const int lane = tid & 63;
  const int wv   = tid >> 6;
  const int len  = lens[b];
  const float w  = vls[b];

  const float* __restrict__ srow = s1s2 + (size_t)b * T_LEN * 2;
  const float* __restrict__ zrow = act  + (size_t)b * T_LEN;

  const int j    = tid;
  const int base = j * CH;

  // ---------- phase 1: batch-load chunk, softmax via single exp, chunk maxima ----------
  float4 sv[8];
  {
    const float4* sp4 = reinterpret_cast<const float4*>(srow + 2 * base);
#pragma unroll
    for (int k = 0; k < 8; k++) sv[k] = sp4[k];
  }
  float4 zv[4];
  {
    const float4* zp4 = reinterpret_cast<const float4*>(zrow + base);
#pragma unroll
    for (int k = 0; k < 4; k++) zv[k] = zp4[k];
  }
  const float* sf = reinterpret_cast<const float*>(sv);
  float z[16];
  {
    const float* zf = reinterpret_cast<const float*>(zv);
#pragma unroll
    for (int i = 0; i < 16; i++) z[i] = zf[i];
  }

  float m1 = NEGV, m2 = NEGV, sp_part = 0.f;
#pragma unroll
  for (int i = 0; i < CH; i++) {
    float lx = sf[2 * i], ly = sf[2 * i + 1];
    float p  = frcp(1.f + __expf(ly - lx));       // p1 = softmax[...,0]
    bool  v  = (base + i) < len;
    float p1m = v ? p : NEGV;
    float p2m = v ? 1.f - p : NEGV;
    P1s[j * PADS + i] = p1m;
    m1 = fmaxf(m1, p1m);
    m2 = fmaxf(m2, p2m);
    float zi = z[i];
    if (v) sp_part += fmaxf(zi, 0.f) + __logf(1.f + __expf(-fabsf(zi)));  // softplus(z)
  }

  // ---------- phase 2: prefix-max scan (m1) + suffix-max scan (m2) over 256 chunks ----------
  {
    float pm = m1;
#pragma unroll
    for (int off = 1; off < 64; off <<= 1) {
      float o = __shfl_up(pm, off);
      if (lane >= off) pm = fmaxf(pm, o);
    }
    float sm = m2;
#pragma unroll
    for (int off = 1; off < 64; off <<= 1) {
      float o = __shfl_down(sm, off);
      if (lane + off < 64) sm = fmaxf(sm, o);
    }
    if (lane == 63) wag1[wv] = pm;   // wave total (prefix side)
    if (lane == 0)  wag2[wv] = sm;   // wave total (suffix side)
    __syncthreads();
    float addp = NEGV, adds = NEGV;
#pragma unroll
    for (int q = 0; q < 4; q++) {
      if (q < wv) addp = fmaxf(addp, wag1[q]);
      if (q > wv) adds = fmaxf(adds, wag2[q]);
    }
    cm1[tid] = fmaxf(pm, addp);
    cm2[tid] = fmaxf(sm, adds);
    __syncthreads();   // also publishes P1s
  }

  // ---------- phase 3: score[t] = pre[t-16] * sigmoid(z[t]) * suf[t+16]; argmax -> ac ----------
  float best = NEGV;
  int   bidx = base;    // all-masked rows reduce to index 0 (matches jnp.argmax)
  {
    float rs[CH];       // suf_s for this chunk (reverse scan over neighbor chunk j+1)
    if (j <= NCH - 2) {
      float run = (j + 2 <= NCH - 1) ? cm2[j + 2] : NEGV;
      const int b2 = (j + 1) * PADS;
#pragma unroll
      for (int i = CH - 1; i >= 0; --i) {
        float p1n = P1s[b2 + i];
        float p2n = (p1n > NEGH) ? 1.f - p1n : NEGV;
        run = fmaxf(run, p2n);
        rs[i] = run;
      }
    }
    float prerun = (j >= 2) ? cm1[j - 2] : NEGV;
    const int b1 = (j - 1) * PADS;
#pragma unroll
    for (int i = 0; i < CH; i++) {
      float pre_s = NEGV;
      if (j >= 1) { prerun = fmaxf(prerun, P1s[b1 + i]); pre_s = prerun; }
      float suf_s = (j <= NCH - 2) ? rs[i] : NEGV;
      int t = base + i;
      if (pre_s > NEGH && suf_s > NEGH && t < len) {
        float pa = frcp(1.f + __expf(-z[i]));
        float sc = (pre_s * pa) * suf_s;
        if (sc > best) { best = sc; bidx = t; }   // strict > keeps first occurrence
      }
    }
  }
#pragma unroll
  for (int off = 32; off; off >>= 1) {
    float ov = __shfl_down(best, off);
    int   oi = __shfl_down(bidx, off);
    amax_comb(best, bidx, ov, oi);
  }
  if (lane == 0) { redv[wv] = best; redi[wv] = bidx; }
  __syncthreads();
  // every thread combines the 4 wave candidates redundantly (saves one barrier;
  // integer argmax -> identical result in all threads, bit-exact vs broadcast)
  int ac;
  {
    float v = redv[0]; int i = redi[0];
#pragma unroll
    for (int q = 1; q < 4; q++) amax_comb(v, i, redv[q], redi[q]);
    ac = i;
  }

  // ---------- phase 4: s1 = argmax p1m on [0, ac-16]; s2 = argmax p2m on [ac+16, T) ----------
  float v1 = NEGV; int i1 = 0;
  float v2 = NEGV; int i2 = 0;
  {
    const int e1   = ac - CH;
    const int s2lo = ac + CH;
#pragma unroll
    for (int k = 0; k < CH; k++) {
      int t = base + k;
      float p1v = P1s[j * PADS + k];
      if (t <= e1 && p1v > v1) { v1 = p1v; i1 = t; }
      float p2v = (p1v > NEGH) ? 1.f - p1v : NEGV;
      if (t >= s2lo && p2v > v2) { v2 = p2v; i2 = t; }
    }
#pragma unroll
    for (int off = 32; off; off >>= 1) {
      float ov1 = __shfl_down(v1, off); int oi1 = __shfl_down(i1, off);
      amax_comb(v1, i1, ov1, oi1);
      float ov2 = __shfl_down(v2, off); int oi2 = __shfl_down(i2, off);
      amax_comb(v2, i2, ov2, oi2);
    }
    if (lane == 0) { redv2[wv] = v1; redi2[wv] = i1; redv3[wv] = v2; redi3[wv] = i2; }
  }

  // ---------- phase 5: action window correction + block sum + output ----------
  if (tid < 9) {
    int t = ac - 4 + tid;
    if (t >= 0 && t < len) {
      float zc = zrow[t];
      float b0 = fmaxf(zc, 0.f) + __logf(1.f + __expf(-fabsf(zc)));  // softplus(z)
      sp_part += 10.f * (b0 - zc) - b0;   // 10*softplus(-z) replaces softplus(z)
    }
  }
  float s = sp_part;
#pragma unroll
  for (int off = 32; off; off >>= 1) s += __shfl_down(s, off);
  if (lane == 0) wag1[wv] = s;
  __syncthreads();
  if (tid == 0) {
    float tot = wag1[0] + wag1[1] + wag1[2] + wag1[3];

    float sv1 = redv2[0]; int s1 = redi2[0];
    float sv2 = redv3[0]; int s2 = redi3[0];
    for (int q = 1; q < 4; q++) {
      amax_comb(sv1, s1, redv2[q], redi2[q]);
      amax_comb(sv2, s2, redv3[q], redi3[q]);
    }
    // state CE: -log_softmax[s1,0] = softplus(l1-l0); -log_softmax[s2,1] = softplus(l0-l1)
    float a0 = srow[2 * (size_t)s1],     a1 = srow[2 * (size_t)s1 + 1];
    float c0 = srow[2 * (size_t)s2],     c1 = srow[2 * (size_t)s2 + 1];
    float d1 = a1 - a0;
    float loss1 = fmaxf(d1, 0.f) + __logf(1.f + __expf(-fabsf(d1)));
    float d2 = c0 - c1;
    float loss2 = fmaxf(d2, 0.f) + __logf(1.f + __expf(-fabsf(d2)));

    ws[2 * (size_t)b]     = w * (loss1 + loss2);
    ws[2 * (size_t)b + 1] = 0.2f * w * tot;
  }
}

__global__ void lftc_reduce(const float* __restrict__ ws, float* __restrict__ out, int B) {
  __shared__ float a0[4], a1[4];
  const int tid  = threadIdx.x;
  const int lane = tid & 63;
  const int wv   = tid >> 6;
  float s0 = 0.f, s1 = 0.f;
  for (int i = tid; i < B; i += 256) {
    s0 += ws[2 * (size_t)i];
    s1 += ws[2 * (size_t)i + 1];
  }
#pragma unroll
  for (int off = 32; off; off >>= 1) {
    s0 += __shfl_down(s0, off);
    s1 += __shfl_down(s1, off);
  }
  if (lane == 0) { a0[wv] = s0; a1[wv] = s1; }
  __syncthreads();
  if (tid == 0) {
    out[0] = a0[0] + a0[1] + a0[2] + a0[3];
    out[1] = a1[0] + a1[1] + a1[2] + a1[3];
  }
}

extern "C" void kernel_launch(void* const* d_in, const int* in_sizes, int n_in,
                              void* d_out, int out_size, void* d_ws, size_t ws_size,
                              hipStream_t stream) {
  const float* s1s2 = (const float*)d_in[0];
  const float* act  = (const float*)d_in[1];
  const int*   lens = (const int*)d_in[2];
  const float* vls  = (const float*)d_in[3];
  float* out = (float*)d_out;
  float* ws  = (float*)d_ws;

  const int B = in_sizes[2];   // lens has B elements; T fixed at 4096

  lftc_main<<<B, 256, 0, stream>>>(s1s2, act, lens, vls, ws);
  lftc_reduce<<<1, 256, 0, stream>>>(ws, out, B);
}

// Round 3
// 99.126 us; speedup vs baseline: 1.1094x; 1.0044x over previous
//
#include <hip/hip_runtime.h>
#include <math.h>

// One block (256 threads) per video row. T = 4096 = 256 chunks x 16 (CH == DELTA).
// Thread j owns chunk j: loads it as float4s, keeps z[16] in registers, computes
// chunk maxima in registers, stores masked p1 to LDS (p2 = 1-p1 recomputed on read).
// Prefix/suffix cummax over 256 chunk maxima via wave shuffles + 4-wave combine.
// Per-block partial losses go to d_ws; a second tiny kernel reduces to d_out.
//
// R1 post-mortem: single-kernel fusion (threadfence+ticket) REGRESSED +11 us —
// per-block device-scope release costs an L2 writeback per block (XCD L2s
// non-coherent). Separate reduce launch is the cheap device-wide barrier.
// R3: chunks fully beyond len skip their global loads entirely (mean len =
// 0.75*T -> ~25% fewer bytes fetched; bit-exact since all consumers of the
// skipped data are already predicated on t < len).

#define T_LEN 4096
#define NCH   256
#define CH    16
#define PADS  17       // padded chunk stride: bank (17j+i)%32 -> 2-way max (free)
#define NEGV  (-1e30f)
#define NEGH  (-5e29f)

__device__ __forceinline__ float frcp(float x) { return __builtin_amdgcn_rcpf(x); }

__device__ __forceinline__ void amax_comb(float& v, int& i, float ov, int oi) {
  // argmax, first-occurrence (smallest index) tie-break — matches jnp.argmax
  if (ov > v || (ov == v && oi < i)) { v = ov; i = oi; }
}

__global__ __launch_bounds__(256, 4) void lftc_main(
    const float* __restrict__ s1s2,  // [B, T, 2]
    const float* __restrict__ act,   // [B, T]
    const int*   __restrict__ lens,  // [B]
    const float* __restrict__ vls,   // [B]
    float* __restrict__ ws)          // [B, 2]: {state_partial, action_partial}
{
  __shared__ float P1s[NCH * PADS];          // masked p1 (p2 = 1-p1 where valid)
  __shared__ float cm1[NCH];                 // inclusive prefix-max of chunk p1-maxima
  __shared__ float cm2[NCH];                 // inclusive suffix-max of chunk p2-maxima
  __shared__ float wag1[4], wag2[4];
  __shared__ float redv[4];  __shared__ int redi[4];
  __shared__ float redv2[4]; __shared__ int redi2[4];
  __shared__ float redv3[4]; __shared__ int redi3[4];

  const int b    = blockIdx.x;
  const int tid  = threadIdx.x;
  const int lane = tid & 63;
  const int wv   = tid >> 6;
  const int len  = lens[b];
  const float w  = vls[b];

  const float* __restrict__ srow = s1s2 + (size_t)b * T_LEN * 2;
  const float* __restrict__ zrow = act  + (size_t)b * T_LEN;

  const int j    = tid;
  const int base = j * CH;

  // ---------- phase 1: batch-load chunk, softmax via single exp, chunk maxima ----------
  // Chunks fully beyond len (base >= len) skip both global loads: every consumer
  // of z[] / sf[] is predicated on t < len, and their P1s stripe is all-NEGV.
  float z[16];
  float m1 = NEGV, m2 = NEGV, sp_part = 0.f;
  if (base < len) {
    float4 sv[8];
    {
      const float4* sp4 = reinterpret_cast<const float4*>(srow + 2 * base);
#pragma unroll
      for (int k = 0; k < 8; k++) sv[k] = sp4[k];
    }
    float4 zv[4];
    {
      const float4* zp4 = reinterpret_cast<const float4*>(zrow + base);
#pragma unroll
      for (int k = 0; k < 4; k++) zv[k] = zp4[k];
    }
    const float* sf = reinterpret_cast<const float*>(sv);
    {
      const float* zf = reinterpret_cast<const float*>(zv);
#pragma unroll
      for (int i = 0; i < 16; i++) z[i] = zf[i];
    }
#pragma unroll
    for (int i = 0; i < CH; i++) {
      float lx = sf[2 * i], ly = sf[2 * i + 1];
      float p  = frcp(1.f + __expf(ly - lx));       // p1 = softmax[...,0]
      bool  v  = (base + i) < len;
      float p1m = v ? p : NEGV;
      float p2m = v ? 1.f - p : NEGV;
      P1s[j * PADS + i] = p1m;
      m1 = fmaxf(m1, p1m);
      m2 = fmaxf(m2, p2m);
      float zi = z[i];
      if (v) sp_part += fmaxf(zi, 0.f) + __logf(1.f + __expf(-fabsf(zi)));  // softplus(z)
    }
  } else {
#pragma unroll
    for (int i = 0; i < CH; i++) {
      P1s[j * PADS + i] = NEGV;
      z[i] = 0.f;   // never consumed (all t >= len), init to keep codegen clean
    }
  }

  // ---------- phase 2: prefix-max scan (m1) + suffix-max scan (m2) over 256 chunks ----------
  {
    float pm = m1;
#pragma unroll
    for (int off = 1; off < 64; off <<= 1) {
      float o = __shfl_up(pm, off);
      if (lane >= off) pm = fmaxf(pm, o);
    }
    float sm = m2;
#pragma unroll
    for (int off = 1; off < 64; off <<= 1) {
      float o = __shfl_down(sm, off);
      if (lane + off < 64) sm = fmaxf(sm, o);
    }
    if (lane == 63) wag1[wv] = pm;   // wave total (prefix side)
    if (lane == 0)  wag2[wv] = sm;   // wave total (suffix side)
    __syncthreads();
    float addp = NEGV, adds = NEGV;
#pragma unroll
    for (int q = 0; q < 4; q++) {
      if (q < wv) addp = fmaxf(addp, wag1[q]);
      if (q > wv) adds = fmaxf(adds, wag2[q]);
    }
    cm1[tid] = fmaxf(pm, addp);
    cm2[tid] = fmaxf(sm, adds);
    __syncthreads();   // also publishes P1s
  }

  // ---------- phase 3: score[t] = pre[t-16] * sigmoid(z[t]) * suf[t+16]; argmax -> ac ----------
  float best = NEGV;
  int   bidx = base;    // all-masked rows reduce to index 0 (matches jnp.argmax)
  {
    float rs[CH];       // suf_s for this chunk (reverse scan over neighbor chunk j+1)
    if (j <= NCH - 2) {
      float run = (j + 2 <= NCH - 1) ? cm2[j + 2] : NEGV;
      const int b2 = (j + 1) * PADS;
#pragma unroll
      for (int i = CH - 1; i >= 0; --i) {
        float p1n = P1s[b2 + i];
        float p2n = (p1n > NEGH) ? 1.f - p1n : NEGV;
        run = fmaxf(run, p2n);
        rs[i] = run;
      }
    }
    float prerun = (j >= 2) ? cm1[j - 2] : NEGV;
    const int b1 = (j - 1) * PADS;
#pragma unroll
    for (int i = 0; i < CH; i++) {
      float pre_s = NEGV;
      if (j >= 1) { prerun = fmaxf(prerun, P1s[b1 + i]); pre_s = prerun; }
      float suf_s = (j <= NCH - 2) ? rs[i] : NEGV;
      int t = base + i;
      if (pre_s > NEGH && suf_s > NEGH && t < len) {
        float pa = frcp(1.f + __expf(-z[i]));
        float sc = (pre_s * pa) * suf_s;
        if (sc > best) { best = sc; bidx = t; }   // strict > keeps first occurrence
      }
    }
  }
#pragma unroll
  for (int off = 32; off; off >>= 1) {
    float ov = __shfl_down(best, off);
    int   oi = __shfl_down(bidx, off);
    amax_comb(best, bidx, ov, oi);
  }
  if (lane == 0) { redv[wv] = best; redi[wv] = bidx; }
  __syncthreads();
  // every thread combines the 4 wave candidates redundantly (saves one barrier;
  // integer argmax -> identical result in all threads, bit-exact vs broadcast)
  int ac;
  {
    float v = redv[0]; int i = redi[0];
#pragma unroll
    for (int q = 1; q < 4; q++) amax_comb(v, i, redv[q], redi[q]);
    ac = i;
  }

  // ---------- phase 4: s1 = argmax p1m on [0, ac-16]; s2 = argmax p2m on [ac+16, T) ----------
  float v1 = NEGV; int i1 = 0;
  float v2 = NEGV; int i2 = 0;
  {
    const int e1   = ac - CH;
    const int s2lo = ac + CH;
#pragma unroll
    for (int k = 0; k < CH; k++) {
      int t = base + k;
      float p1v = P1s[j * PADS + k];
      if (t <= e1 && p1v > v1) { v1 = p1v; i1 = t; }
      float p2v = (p1v > NEGH) ? 1.f - p1v : NEGV;
      if (t >= s2lo && p2v > v2) { v2 = p2v; i2 = t; }
    }
#pragma unroll
    for (int off = 32; off; off >>= 1) {
      float ov1 = __shfl_down(v1, off); int oi1 = __shfl_down(i1, off);
      amax_comb(v1, i1, ov1, oi1);
      float ov2 = __shfl_down(v2, off); int oi2 = __shfl_down(i2, off);
      amax_comb(v2, i2, ov2, oi2);
    }
    if (lane == 0) { redv2[wv] = v1; redi2[wv] = i1; redv3[wv] = v2; redi3[wv] = i2; }
  }

  // ---------- phase 5: action window correction + block sum + output ----------
  if (tid < 9) {
    int t = ac - 4 + tid;
    if (t >= 0 && t < len) {
      float zc = zrow[t];
      float b0 = fmaxf(zc, 0.f) + __logf(1.f + __expf(-fabsf(zc)));  // softplus(z)
      sp_part += 10.f * (b0 - zc) - b0;   // 10*softplus(-z) replaces softplus(z)
    }
  }
  float s = sp_part;
#pragma unroll
  for (int off = 32; off; off >>= 1) s += __shfl_down(s, off);
  if (lane == 0) wag1[wv] = s;
  __syncthreads();
  if (tid == 0) {
    float tot = wag1[0] + wag1[1] + wag1[2] + wag1[3];

    float sv1 = redv2[0]; int s1 = redi2[0];
    float sv2 = redv3[0]; int s2 = redi3[0];
    for (int q = 1; q < 4; q++) {
      amax_comb(sv1, s1, redv2[q], redi2[q]);
      amax_comb(sv2, s2, redv3[q], redi3[q]);
    }
    // state CE: -log_softmax[s1,0] = softplus(l1-l0); -log_softmax[s2,1] = softplus(l0-l1)
    float a0 = srow[2 * (size_t)s1],     a1 = srow[2 * (size_t)s1 + 1];
    float c0 = srow[2 * (size_t)s2],     c1 = srow[2 * (size_t)s2 + 1];
    float d1 = a1 - a0;
    float loss1 = fmaxf(d1, 0.f) + __logf(1.f + __expf(-fabsf(d1)));
    float d2 = c0 - c1;
    float loss2 = fmaxf(d2, 0.f) + __logf(1.f + __expf(-fabsf(d2)));

    ws[2 * (size_t)b]     = w * (loss1 + loss2);
    ws[2 * (size_t)b + 1] = 0.2f * w * tot;
  }
}

__global__ void lftc_reduce(const float* __restrict__ ws, float* __restrict__ out, int B) {
  __shared__ float a0[4], a1[4];
  const int tid  = threadIdx.x;
  const int lane = tid & 63;
  const int wv   = tid >> 6;
  float s0 = 0.f, s1 = 0.f;
  for (int i = tid; i < B; i += 256) {
    s0 += ws[2 * (size_t)i];
    s1 += ws[2 * (size_t)i + 1];
  }
#pragma unroll
  for (int off = 32; off; off >>= 1) {
    s0 += __shfl_down(s0, off);
    s1 += __shfl_down(s1, off);
  }
  if (lane == 0) { a0[wv] = s0; a1[wv] = s1; }
  __syncthreads();
  if (tid == 0) {
    out[0] = a0[0] + a0[1] + a0[2] + a0[3];
    out[1] = a1[0] + a1[1] + a1[2] + a1[3];
  }
}

extern "C" void kernel_launch(void* const* d_in, const int* in_sizes, int n_in,
                              void* d_out, int out_size, void* d_ws, size_t ws_size,
                              hipStream_t stream) {
  const float* s1s2 = (const float*)d_in[0];
  const float* act  = (const float*)d_in[1];
  const int*   lens = (const int*)d_in[2];
  const float* vls  = (const float*)d_in[3];
  float* out = (float*)d_out;
  float* ws  = (float*)d_ws;

  const int B = in_sizes[2];   // lens has B elements; T fixed at 4096

  lftc_main<<<B, 256, 0, stream>>>(s1s2, act, lens, vls, ws);
  lftc_reduce<<<1, 256, 0, stream>>>(ws, out, B);
}